// Round 11
// baseline (132.141 us; speedup 1.0000x reference)
//
#include <hip/hip_runtime.h>

#define IMG  12
#define NPIX 144
#define THREADS 256

// Wave-uniform float -> SGPR (VOP3 FMA takes one SGPR operand free)
__device__ __forceinline__ float rfl(float v) {
    return __builtin_bit_cast(float, __builtin_amdgcn_readfirstlane(__builtin_bit_cast(int, v)));
}

// One thread = one OUTPUT ROW r of one image (12 threads/image, 1.2M threads).
// O row r needs only T row r = Wq[r,:] @ X  ->  stage1+stage2 fused in registers,
// no T transpose, no LDS round-trip, no barrier in the hot path.
__global__ __launch_bounds__(THREADS, 4)   // cap VGPR at 128 -> 16 waves/CU
void dft_apx_kernel(const float* __restrict__ x,
                    const float* __restrict__ wr,
                    const float* __restrict__ wi,
                    float* __restrict__ out, int size)
{
    // Full quantized W (row-major) in LDS: W[r][j] = table[(r*j)%12], where the
    // table is weight row 1 (wr[12+m] = cos(2pi m/12)+1e-5). Needed because a
    // thread's row r is runtime -> can't compile-time index the SGPR table.
    __shared__ float wqc[NPIX], wqs[NPIX];

    const int tid = threadIdx.x;
    if (tid < NPIX) {
        const int r = tid / IMG, j = tid - r * IMG;
        const int m = (r * j) % IMG;
        wqc[tid] = rintf(wr[IMG + m] * 65535.0f);
        wqs[tid] = rintf(wi[IMG + m] * 65535.0f);
    }

    // 12-entry tables in SGPRs for stage 2 ((j*c)%12 is compile-time there)
    float cq[12], sq[12];
    #pragma unroll
    for (int m = 0; m < 12; ++m) {
        cq[m] = rfl(rintf(wr[IMG + m] * 65535.0f));
        sq[m] = rfl(rintf(wi[IMG + m] * 65535.0f));
    }
    __syncthreads();   // wq table ready; no barriers after this

    const int g   = blockIdx.x * THREADS + tid;   // < 1,200,128 fits int
    const int img = g / IMG;                      // magic-mul division
    const int r   = g - img * IMG;
    if (img >= size) return;

    // Weight row r from LDS: 6x ds_read_b128, 2-way bank aliasing at worst (free).
    float cr[12], sr[12];
    #pragma unroll
    for (int q = 0; q < 3; ++q) {
        const float4 a = *(const float4*)&wqc[r * IMG + 4*q];
        const float4 b = *(const float4*)&wqs[r * IMG + 4*q];
        cr[4*q+0]=a.x; cr[4*q+1]=a.y; cr[4*q+2]=a.z; cr[4*q+3]=a.w;
        sr[4*q+0]=b.x; sr[4*q+1]=b.y; sr[4*q+2]=b.z; sr[4*q+3]=b.w;
    }

    // ---- stage 1: T row r = Wq[r,:] @ X, X streamed row-by-row from global.
    // 12 lanes of an image read identical addresses (request-merged, L1-hot);
    // X never occupies >1 row of registers -> no spill. j-ascending fmaf order
    // is bit-identical to the validated kernels.
    const float* xim = x + (size_t)img * NPIX;
    float rt[12] = {0,0,0,0,0,0,0,0,0,0,0,0};
    float it[12] = {0,0,0,0,0,0,0,0,0,0,0,0};
    #pragma unroll
    for (int j = 0; j < 12; ++j) {
        const float4 v0 = *(const float4*)(xim + j * IMG + 0);
        const float4 v1 = *(const float4*)(xim + j * IMG + 4);
        const float4 v2 = *(const float4*)(xim + j * IMG + 8);
        const float xv[12] = {v0.x,v0.y,v0.z,v0.w, v1.x,v1.y,v1.z,v1.w, v2.x,v2.y,v2.z,v2.w};
        const float wc = cr[j], ws = sr[j];
        #pragma unroll
        for (int c = 0; c < 12; ++c) {
            rt[c] = fmaf(wc, xv[c], rt[c]);
            it[c] = fmaf(ws, xv[c], it[c]);
        }
    }

    // ---- stage 2: O[r][c] = sum_j T[r][j]*Wq[j][c]; |O| * 2^-32 ----
    const float inv32 = 2.3283064365386963e-10f;  // 2^-32, exact pow2
    float o[12];
    #pragma unroll
    for (int c = 0; c < 12; ++c) {
        float ro = 0.0f, io = 0.0f;
        #pragma unroll
        for (int j = 0; j < 12; ++j) {
            const int m = (j * c) % 12;           // compile-time after unroll
            ro = fmaf(rt[j],  cq[m], ro);
            ro = fmaf(-it[j], sq[m], ro);
            io = fmaf(rt[j],  sq[m], io);
            io = fmaf(it[j],  cq[m], io);
        }
        o[c] = __builtin_amdgcn_sqrtf(fmaf(ro, ro, io * io)) * inv32;
    }

    // Store row r: consecutive lanes -> consecutive 48B -> fully coalesced.
    float4* orow = (float4*)(out + (size_t)img * NPIX + r * IMG);
    orow[0] = make_float4(o[0], o[1], o[2],  o[3]);
    orow[1] = make_float4(o[4], o[5], o[6],  o[7]);
    orow[2] = make_float4(o[8], o[9], o[10], o[11]);
}

extern "C" void kernel_launch(void* const* d_in, const int* in_sizes, int n_in,
                              void* d_out, int out_size, void* d_ws, size_t ws_size,
                              hipStream_t stream) {
    const float* x  = (const float*)d_in[0];   // (1, 100000, 12, 12) f32
    const float* wr = (const float*)d_in[1];   // (1, 144) f32
    const float* wi = (const float*)d_in[2];   // (1, 144) f32
    float* out = (float*)d_out;                // (1,1,100000,12,12) f32

    const int size = in_sizes[0] / NPIX;                      // 100000
    const int threads_total = size * IMG;                     // 1.2M
    const int blocks = (threads_total + THREADS - 1) / THREADS;  // 4688
    dft_apx_kernel<<<blocks, THREADS, 0, stream>>>(x, wr, wi, out, size);
}